// Round 1
// baseline (161.977 us; speedup 1.0000x reference)
//
#include <hip/hip_runtime.h>

#define BB 8
#define SS 8192
#define NN 16
#define DD 64
#define MM 64
#define TS 32   // s-rows staged per LDS tile

__device__ __forceinline__ float feat(float x) {
    // elu(x) + 1 == x+1 (x>0), exp(x) (x<=0)
    return x > 0.0f ? (x + 1.0f) : __expf(x);
}

// One block per (bn, chunk). 256 threads; thread t owns a 4x4 (m,d) register
// tile: d0=(t&15)*4, m0=(t>>4)*4. Accumulates partial Sst[64][64] and Z[64]
// over its S-chunk; writes partials (4096+64 floats) to ws.
__global__ __launch_bounds__(256)
void rcla_partial(const float* __restrict__ key,
                  const float* __restrict__ value,
                  const int* __restrict__ mask,
                  float* __restrict__ ws, int C) {
    const int blk = blockIdx.x;
    const int c  = blk % C;
    const int bn = blk / C;
    const int b  = bn >> 4;   // N = 16
    const int n  = bn & 15;
    const int t  = threadIdx.x;
    const int d0 = (t & 15) << 2;
    const int m0 = (t >> 4) << 2;

    __shared__ float Kt[TS][DD];
    __shared__ float Vt[TS][MM];

    const int steps   = SS / C;       // C in {1,2,4,8}: divides 8192, TS divides steps
    const int s_begin = c * steps;

    const float* kb = key   + (((size_t)b * SS) * NN + n) * DD;
    const float* vb = value + (((size_t)b * SS) * NN + n) * MM;
    const int*   mb = mask  + (size_t)b * SS;

    float acc[4][4] = {{0.f,0.f,0.f,0.f},{0.f,0.f,0.f,0.f},
                       {0.f,0.f,0.f,0.f},{0.f,0.f,0.f,0.f}};
    float zacc[4]   = {0.f,0.f,0.f,0.f};

    for (int ss = 0; ss < steps; ss += TS) {
        const int sb = s_begin + ss;
        // Stage TS rows of K (feature-mapped+masked) and V into LDS.
        // 512 float4 per tensor per tile -> 2 float4 per thread per tensor.
        #pragma unroll
        for (int u = 0; u < 2; ++u) {
            const int f   = t + u * 256;
            const int row = f >> 4;
            const int col = (f & 15) << 2;
            const int s   = sb + row;
            const bool live = (mb[s] == 0);   // mask True -> zero out key row
            float4 kv = make_float4(0.f, 0.f, 0.f, 0.f);
            float4 vv = make_float4(0.f, 0.f, 0.f, 0.f);
            if (live) {
                kv = *reinterpret_cast<const float4*>(kb + (size_t)s * (NN * DD) + col);
                vv = *reinterpret_cast<const float4*>(vb + (size_t)s * (NN * MM) + col);
                kv.x = feat(kv.x); kv.y = feat(kv.y);
                kv.z = feat(kv.z); kv.w = feat(kv.w);
            }
            *reinterpret_cast<float4*>(&Kt[row][col]) = kv;
            *reinterpret_cast<float4*>(&Vt[row][col]) = vv;
        }
        __syncthreads();

        #pragma unroll 8
        for (int r = 0; r < TS; ++r) {
            const float4 kq = *reinterpret_cast<const float4*>(&Kt[r][d0]);
            const float4 vq = *reinterpret_cast<const float4*>(&Vt[r][m0]);
            const float ka[4] = {kq.x, kq.y, kq.z, kq.w};
            const float va[4] = {vq.x, vq.y, vq.z, vq.w};
            #pragma unroll
            for (int i = 0; i < 4; ++i)
                #pragma unroll
                for (int j = 0; j < 4; ++j)
                    acc[i][j] += va[i] * ka[j];
            if (t < 16) {   // one m-group accumulates Z (shares the K LDS read)
                #pragma unroll
                for (int j = 0; j < 4; ++j) zacc[j] += ka[j];
            }
        }
        __syncthreads();
    }

    float* p = ws + ((size_t)bn * C + c) * 4160;   // 4096 Sst + 64 Z
    #pragma unroll
    for (int i = 0; i < 4; ++i) {
        *reinterpret_cast<float4*>(p + (m0 + i) * DD + d0) =
            make_float4(acc[i][0], acc[i][1], acc[i][2], acc[i][3]);
    }
    if (t < 16) {
        *reinterpret_cast<float4*>(p + 4096 + d0) =
            make_float4(zacc[0], zacc[1], zacc[2], zacc[3]);
    }
}

// One block per (b,n): reduce C partials, emit Sst and Z, then
// QZ = 1/(dot(feat(q),Z)+eps) and V[m] = QZ * sum_d feat(q)[d]*Sst[m,d].
__global__ __launch_bounds__(256)
void rcla_final(const float* __restrict__ query,
                const float* __restrict__ ws, int C,
                float* __restrict__ outV, float* __restrict__ outS,
                float* __restrict__ outZ) {
    const int bn = blockIdx.x;
    const int t  = threadIdx.x;
    const int d0 = (t & 15) << 2;
    const int m0 = (t >> 4) << 2;
    const float* p0 = ws + (size_t)bn * C * 4160;

    float sst[4][4] = {{0.f,0.f,0.f,0.f},{0.f,0.f,0.f,0.f},
                       {0.f,0.f,0.f,0.f},{0.f,0.f,0.f,0.f}};
    float z[4] = {0.f,0.f,0.f,0.f};

    for (int c = 0; c < C; ++c) {
        const float* p = p0 + (size_t)c * 4160;
        #pragma unroll
        for (int i = 0; i < 4; ++i) {
            const float4 v = *reinterpret_cast<const float4*>(p + (m0 + i) * DD + d0);
            sst[i][0] += v.x; sst[i][1] += v.y; sst[i][2] += v.z; sst[i][3] += v.w;
        }
        if (t < 16) {
            const float4 zv = *reinterpret_cast<const float4*>(p + 4096 + d0);
            z[0] += zv.x; z[1] += zv.y; z[2] += zv.z; z[3] += zv.w;
        }
    }

    // Output 1: Sst [b,n,m,d]
    #pragma unroll
    for (int i = 0; i < 4; ++i) {
        *reinterpret_cast<float4*>(outS + (size_t)bn * 4096 + (m0 + i) * DD + d0) =
            make_float4(sst[i][0], sst[i][1], sst[i][2], sst[i][3]);
    }
    // Output 2: Z [b,n,d]
    if (t < 16) {
        *reinterpret_cast<float4*>(outZ + (size_t)bn * DD + d0) =
            make_float4(z[0], z[1], z[2], z[3]);
    }

    // feat(query) for this thread's d-range
    float qf[4];
    #pragma unroll
    for (int j = 0; j < 4; ++j) qf[j] = feat(query[(size_t)bn * DD + d0 + j]);

    __shared__ float qz_sh;
    if (t < 64) {   // wave 0: dot(feat(q), Z) lives in lanes 0..15
        float pd = 0.f;
        if (t < 16) pd = qf[0]*z[0] + qf[1]*z[1] + qf[2]*z[2] + qf[3]*z[3];
        pd += __shfl_xor(pd, 1);
        pd += __shfl_xor(pd, 2);
        pd += __shfl_xor(pd, 4);
        pd += __shfl_xor(pd, 8);
        if (t == 0) qz_sh = 1.0f / (pd + 1e-6f);
    }
    __syncthreads();
    const float qz = qz_sh;

    // Output 0: V[m] = qz * sum_d qf[d]*Sst[m,d]; reduce across the 16
    // threads (same wave, consecutive lanes) sharing this m-group.
    float pv[4];
    #pragma unroll
    for (int i = 0; i < 4; ++i)
        pv[i] = qf[0]*sst[i][0] + qf[1]*sst[i][1] + qf[2]*sst[i][2] + qf[3]*sst[i][3];
    #pragma unroll
    for (int off = 1; off < 16; off <<= 1) {
        #pragma unroll
        for (int i = 0; i < 4; ++i) pv[i] += __shfl_xor(pv[i], off);
    }
    if ((t & 15) == 0) {
        #pragma unroll
        for (int i = 0; i < 4; ++i)
            outV[(size_t)bn * MM + m0 + i] = qz * pv[i];
    }
}

extern "C" void kernel_launch(void* const* d_in, const int* in_sizes, int n_in,
                              void* d_out, int out_size, void* d_ws, size_t ws_size,
                              hipStream_t stream) {
    const float* query = (const float*)d_in[0];
    const float* key   = (const float*)d_in[1];
    const float* value = (const float*)d_in[2];
    const int*   mask  = (const int*)d_in[3];

    float* out  = (float*)d_out;
    float* outV = out;                         // [B,N,M]   8192
    float* outS = out + BB * NN * MM;          // [B,N,M,D] 524288
    float* outZ = outS + BB * NN * MM * DD;    // [B,N,D]   8192
    float* ws   = (float*)d_ws;

    int C = 8;   // S-chunks per (b,n); shrink if workspace is small
    while (C > 1 && (size_t)BB * NN * C * 4160 * sizeof(float) > ws_size) C >>= 1;

    rcla_partial<<<dim3(BB * NN * C), dim3(256), 0, stream>>>(key, value, mask, ws, C);
    rcla_final<<<dim3(BB * NN), dim3(256), 0, stream>>>(query, ws, C, outV, outS, outZ);
}

// Round 2
// 86.409 us; speedup vs baseline: 1.8745x; 1.8745x over previous
//
#include <hip/hip_runtime.h>
#include <hip/hip_bf16.h>
#include <stdint.h>

#define BB 8
#define SS 8192
#define NN 16
#define DD 64
#define MM 64
#define TS 32    // s-rows per LDS tile
#define PAD 40   // row stride (bf16 elems) for transposed LDS tiles: 80 B, 16B-aligned rows

typedef __attribute__((ext_vector_type(8))) short bf16x8;
typedef __attribute__((ext_vector_type(4))) float f32x4;

__device__ __forceinline__ float feat(float x) {
    // elu(x) + 1 == x+1 (x>0), exp(x) (x<=0)
    return x > 0.0f ? (x + 1.0f) : __expf(x);
}

__device__ __forceinline__ uint32_t bf16bits(float x) {
    __hip_bfloat16 h = __float2bfloat16(x);   // RNE
    return (uint32_t)*reinterpret_cast<unsigned short*>(&h);
}

// One block per (bn, chunk). 256 threads = 4 waves; wave w owns the 32x32
// output quadrant (wm, wd) = ((w>>1)*32, (w&1)*32) of Sst[64][64].
// LDS tiles are stored transposed: Klds[d][s], Vlds[m][s] (bf16), so MFMA
// A/B fragments are 8 contiguous bf16 per lane (one ds_read_b128).
__global__ __launch_bounds__(256)
void rcla_partial(const float* __restrict__ key,
                  const float* __restrict__ value,
                  const int* __restrict__ mask,
                  float* __restrict__ ws, int C) {
    const int blk = blockIdx.x;
    const int c  = blk % C;
    const int bn = blk / C;
    const int b  = bn >> 4;   // N = 16
    const int n  = bn & 15;
    const int t  = threadIdx.x;

    // staging mapping: thread t handles columns c0..c0+3 of rows sl, sl+1
    const int a  = t & 15;
    const int p  = t >> 4;        // 0..15
    const int c0 = a << 2;        // d (for K) and m (for V)
    const int sl = p << 1;        // local s (even)

    // MFMA mapping
    const int lane = t & 63;
    const int w    = t >> 6;
    const int wm   = (w >> 1) << 5;
    const int wd   = (w & 1) << 5;
    const int g    = lane >> 4;   // k-group
    const int lr   = lane & 15;   // row-in-frag / col-in-C

    __shared__ __hip_bfloat16 Klds[DD][PAD];
    __shared__ __hip_bfloat16 Vlds[MM][PAD];
    __shared__ float Zred[16][DD];

    const int steps   = SS / C;
    const int s_begin = c * steps;

    const float* kb = key   + (((size_t)b * SS) * NN + n) * DD;
    const float* vb = value + (((size_t)b * SS) * NN + n) * MM;
    const int*   mb = mask  + (size_t)b * SS;

    f32x4 acc[2][2] = {};
    float zacc[4] = {0.f, 0.f, 0.f, 0.f};

    for (int ss = 0; ss < steps; ss += TS) {
        const int s0 = s_begin + ss + sl;
        const bool live0 = (mb[s0] == 0);
        const bool live1 = (mb[s0 + 1] == 0);

        float fk0[4] = {0.f,0.f,0.f,0.f}, fk1[4] = {0.f,0.f,0.f,0.f};
        float fv0[4] = {0.f,0.f,0.f,0.f}, fv1[4] = {0.f,0.f,0.f,0.f};
        if (live0) {
            const float4 kq = *reinterpret_cast<const float4*>(kb + (size_t)s0 * (NN * DD) + c0);
            const float4 vq = *reinterpret_cast<const float4*>(vb + (size_t)s0 * (NN * MM) + c0);
            fk0[0] = feat(kq.x); fk0[1] = feat(kq.y); fk0[2] = feat(kq.z); fk0[3] = feat(kq.w);
            fv0[0] = vq.x; fv0[1] = vq.y; fv0[2] = vq.z; fv0[3] = vq.w;
        }
        if (live1) {
            const float4 kq = *reinterpret_cast<const float4*>(kb + (size_t)(s0 + 1) * (NN * DD) + c0);
            const float4 vq = *reinterpret_cast<const float4*>(vb + (size_t)(s0 + 1) * (NN * MM) + c0);
            fk1[0] = feat(kq.x); fk1[1] = feat(kq.y); fk1[2] = feat(kq.z); fk1[3] = feat(kq.w);
            fv1[0] = vq.x; fv1[1] = vq.y; fv1[2] = vq.z; fv1[3] = vq.w;
        }
        #pragma unroll
        for (int j = 0; j < 4; ++j) {
            zacc[j] += fk0[j] + fk1[j];
            const uint32_t pk = (bf16bits(fk1[j]) << 16) | bf16bits(fk0[j]);
            const uint32_t pv = (bf16bits(fv1[j]) << 16) | bf16bits(fv0[j]);
            *reinterpret_cast<uint32_t*>(&Klds[c0 + j][sl]) = pk;
            *reinterpret_cast<uint32_t*>(&Vlds[c0 + j][sl]) = pv;
        }
        __syncthreads();

        // fragments: A = V^T (rows m, 8 contiguous s), B = K^T (rows d, 8 contiguous s)
        const bf16x8 a0 = *reinterpret_cast<const bf16x8*>(&Vlds[wm + lr][g * 8]);
        const bf16x8 a1 = *reinterpret_cast<const bf16x8*>(&Vlds[wm + 16 + lr][g * 8]);
        const bf16x8 b0 = *reinterpret_cast<const bf16x8*>(&Klds[wd + lr][g * 8]);
        const bf16x8 b1 = *reinterpret_cast<const bf16x8*>(&Klds[wd + 16 + lr][g * 8]);
        acc[0][0] = __builtin_amdgcn_mfma_f32_16x16x32_bf16(a0, b0, acc[0][0], 0, 0, 0);
        acc[0][1] = __builtin_amdgcn_mfma_f32_16x16x32_bf16(a0, b1, acc[0][1], 0, 0, 0);
        acc[1][0] = __builtin_amdgcn_mfma_f32_16x16x32_bf16(a1, b0, acc[1][0], 0, 0, 0);
        acc[1][1] = __builtin_amdgcn_mfma_f32_16x16x32_bf16(a1, b1, acc[1][1], 0, 0, 0);
        __syncthreads();
    }

    // partials: 4096 Sst + 64 Z per (bn, c)
    float* out = ws + ((size_t)bn * C + c) * 4160;

    // C/D layout (verified): col = lane&15, row = (lane>>4)*4 + reg
    #pragma unroll
    for (int i = 0; i < 2; ++i)
        #pragma unroll
        for (int j = 0; j < 2; ++j)
            #pragma unroll
            for (int r = 0; r < 4; ++r) {
                const int m = wm + 16 * i + g * 4 + r;
                const int d = wd + 16 * j + lr;
                out[m * DD + d] = acc[i][j][r];
            }

    // Z reduction: thread (a,p) owns d = c0..c0+3 partial sums
    *reinterpret_cast<float4*>(&Zred[p][c0]) =
        make_float4(zacc[0], zacc[1], zacc[2], zacc[3]);
    __syncthreads();
    if (t < DD) {
        float z = 0.f;
        #pragma unroll
        for (int q = 0; q < 16; ++q) z += Zred[q][t];
        out[4096 + t] = z;
    }
}

// One block per (b,n): reduce C partials, emit Sst and Z, then
// QZ = 1/(dot(feat(q),Z)+eps) and V[m] = QZ * sum_d feat(q)[d]*Sst[m,d].
__global__ __launch_bounds__(256)
void rcla_final(const float* __restrict__ query,
                const float* __restrict__ ws, int C,
                float* __restrict__ outV, float* __restrict__ outS,
                float* __restrict__ outZ) {
    const int bn = blockIdx.x;
    const int t  = threadIdx.x;
    const int d0 = (t & 15) << 2;
    const int m0 = (t >> 4) << 2;
    const float* p0 = ws + (size_t)bn * C * 4160;

    float sst[4][4] = {{0.f,0.f,0.f,0.f},{0.f,0.f,0.f,0.f},
                       {0.f,0.f,0.f,0.f},{0.f,0.f,0.f,0.f}};
    float z[4] = {0.f,0.f,0.f,0.f};

    for (int c = 0; c < C; ++c) {
        const float* p = p0 + (size_t)c * 4160;
        #pragma unroll
        for (int i = 0; i < 4; ++i) {
            const float4 v = *reinterpret_cast<const float4*>(p + (m0 + i) * DD + d0);
            sst[i][0] += v.x; sst[i][1] += v.y; sst[i][2] += v.z; sst[i][3] += v.w;
        }
        if (t < 16) {
            const float4 zv = *reinterpret_cast<const float4*>(p + 4096 + d0);
            z[0] += zv.x; z[1] += zv.y; z[2] += zv.z; z[3] += zv.w;
        }
    }

    #pragma unroll
    for (int i = 0; i < 4; ++i) {
        *reinterpret_cast<float4*>(outS + (size_t)bn * 4096 + (m0 + i) * DD + d0) =
            make_float4(sst[i][0], sst[i][1], sst[i][2], sst[i][3]);
    }
    if (t < 16) {
        *reinterpret_cast<float4*>(outZ + (size_t)bn * DD + d0) =
            make_float4(z[0], z[1], z[2], z[3]);
    }

    float qf[4];
    #pragma unroll
    for (int j = 0; j < 4; ++j) qf[j] = feat(query[(size_t)bn * DD + d0 + j]);

    __shared__ float qz_sh;
    if (t < 64) {
        float pd = 0.f;
        if (t < 16) pd = qf[0]*z[0] + qf[1]*z[1] + qf[2]*z[2] + qf[3]*z[3];
        pd += __shfl_xor(pd, 1);
        pd += __shfl_xor(pd, 2);
        pd += __shfl_xor(pd, 4);
        pd += __shfl_xor(pd, 8);
        if (t == 0) qz_sh = 1.0f / (pd + 1e-6f);
    }
    __syncthreads();
    const float qz = qz_sh;

    float pv[4];
    #pragma unroll
    for (int i = 0; i < 4; ++i)
        pv[i] = qf[0]*sst[i][0] + qf[1]*sst[i][1] + qf[2]*sst[i][2] + qf[3]*sst[i][3];
    #pragma unroll
    for (int off = 1; off < 16; off <<= 1) {
        #pragma unroll
        for (int i = 0; i < 4; ++i) pv[i] += __shfl_xor(pv[i], off);
    }
    if ((t & 15) == 0) {
        #pragma unroll
        for (int i = 0; i < 4; ++i)
            outV[(size_t)bn * MM + m0 + i] = qz * pv[i];
    }
}

extern "C" void kernel_launch(void* const* d_in, const int* in_sizes, int n_in,
                              void* d_out, int out_size, void* d_ws, size_t ws_size,
                              hipStream_t stream) {
    const float* query = (const float*)d_in[0];
    const float* key   = (const float*)d_in[1];
    const float* value = (const float*)d_in[2];
    const int*   mask  = (const int*)d_in[3];

    float* out  = (float*)d_out;
    float* outV = out;                         // [B,N,M]   8192
    float* outS = out + BB * NN * MM;          // [B,N,M,D] 524288
    float* outZ = outS + BB * NN * MM * DD;    // [B,N,D]   8192
    float* ws   = (float*)d_ws;

    int C = 8;
    while (C > 1 && (size_t)BB * NN * C * 4160 * sizeof(float) > ws_size) C >>= 1;

    rcla_partial<<<dim3(BB * NN * C), dim3(256), 0, stream>>>(key, value, mask, ws, C);
    rcla_final<<<dim3(BB * NN), dim3(256), 0, stream>>>(query, ws, C, outV, outS, outZ);
}

// Round 3
// 67.830 us; speedup vs baseline: 2.3880x; 1.2739x over previous
//
#include <hip/hip_runtime.h>
#include <hip/hip_bf16.h>
#include <stdint.h>

#define BB 8
#define SS 8192
#define NN 16
#define DD 64
#define MM 64
#define TS 32    // s-rows per LDS tile
#define PAD 40   // row stride (bf16 elems) for transposed LDS tiles: 80 B, 16B-aligned rows

typedef __attribute__((ext_vector_type(8))) short bf16x8;
typedef __attribute__((ext_vector_type(4))) float f32x4;

__device__ __forceinline__ float feat(float x) {
    // elu(x) + 1 == x+1 (x>0), exp(x) (x<=0)
    return x > 0.0f ? (x + 1.0f) : __expf(x);
}

__device__ __forceinline__ uint32_t bf16bits(float x) {
    __hip_bfloat16 h = __float2bfloat16(x);   // RNE
    return (uint32_t)*reinterpret_cast<unsigned short*>(&h);
}

// One block per (bn, chunk). 256 threads = 4 waves; wave w owns the 32x32
// output quadrant (wm, wd) of Sst[64][64]. LDS tiles stored transposed
// (Klds[d][s], Vlds[m][s], bf16) so MFMA fragments are one ds_read_b128.
// Chunk's mask is preloaded to LDS once; tile t+1's global loads are issued
// before tile t's MFMA phase (T14 issue-early) to hide HBM latency.
__global__ __launch_bounds__(256)
void rcla_partial(const float* __restrict__ key,
                  const float* __restrict__ value,
                  const int* __restrict__ mask,
                  float* __restrict__ ws, int C) {
    const int blk = blockIdx.x;
    const int c  = blk % C;
    const int bn = blk / C;
    const int b  = bn >> 4;   // N = 16
    const int n  = bn & 15;
    const int t  = threadIdx.x;

    // staging mapping: thread t handles columns c0..c0+3 of rows sl, sl+1
    const int a  = t & 15;
    const int p  = t >> 4;        // 0..15
    const int c0 = a << 2;        // d (K) / m (V)
    const int sl = p << 1;        // local s (even)

    // MFMA mapping
    const int lane = t & 63;
    const int w    = t >> 6;
    const int wm   = (w >> 1) << 5;
    const int wd   = (w & 1) << 5;
    const int g    = lane >> 4;   // k-group
    const int lr   = lane & 15;

    __shared__ __hip_bfloat16 Klds[DD][PAD];   // 5120 B
    __shared__ __hip_bfloat16 Vlds[MM][PAD];   // 5120 B
    __shared__ unsigned char  Msk[1024];       // 1024 B (supports C>=8)
    __shared__ float Zred[16][DD];             // 4096 B  -> 15360 total

    const int steps   = SS / C;   // 512 at C=16
    const int s_begin = c * steps;

    const float* kb = key   + (((size_t)b * SS) * NN + n) * DD;
    const float* vb = value + (((size_t)b * SS) * NN + n) * MM;
    const int*   mb = mask  + (size_t)b * SS;

    // preload chunk mask as bytes (one coalesced pass, kills 16x-redundant
    // per-tile mask VMEM loads and the mask->load serial chain)
    for (int i = t; i < steps; i += 256)
        Msk[i] = (unsigned char)(mb[s_begin + i] != 0);
    __syncthreads();

    f32x4 acc[2][2] = {};
    float zacc[4] = {0.f, 0.f, 0.f, 0.f};

    const float4 z4 = make_float4(0.f, 0.f, 0.f, 0.f);
    float4 kq0 = z4, kq1 = z4, vq0 = z4, vq1 = z4;
    bool lv0 = false, lv1 = false;

    // load tile 0 into regs
    {
        const int s0 = s_begin + sl;
        lv0 = (Msk[sl] == 0);
        lv1 = (Msk[sl + 1] == 0);
        if (lv0) {
            kq0 = *reinterpret_cast<const float4*>(kb + (size_t)s0 * (NN * DD) + c0);
            vq0 = *reinterpret_cast<const float4*>(vb + (size_t)s0 * (NN * MM) + c0);
        }
        if (lv1) {
            kq1 = *reinterpret_cast<const float4*>(kb + (size_t)(s0 + 1) * (NN * DD) + c0);
            vq1 = *reinterpret_cast<const float4*>(vb + (size_t)(s0 + 1) * (NN * MM) + c0);
        }
    }

    for (int ss = 0; ss < steps; ss += TS) {
        // feat + cvt + LDS write from the prefetched registers
        {
            const float k0[4] = {kq0.x, kq0.y, kq0.z, kq0.w};
            const float k1[4] = {kq1.x, kq1.y, kq1.z, kq1.w};
            const float v0[4] = {vq0.x, vq0.y, vq0.z, vq0.w};
            const float v1[4] = {vq1.x, vq1.y, vq1.z, vq1.w};
            #pragma unroll
            for (int j = 0; j < 4; ++j) {
                const float fk0 = lv0 ? feat(k0[j]) : 0.f;
                const float fk1 = lv1 ? feat(k1[j]) : 0.f;
                const float fv0 = lv0 ? v0[j] : 0.f;
                const float fv1 = lv1 ? v1[j] : 0.f;
                zacc[j] += fk0 + fk1;
                const uint32_t pk = (bf16bits(fk1) << 16) | bf16bits(fk0);
                const uint32_t pv = (bf16bits(fv1) << 16) | bf16bits(fv0);
                *reinterpret_cast<uint32_t*>(&Klds[c0 + j][sl]) = pk;
                *reinterpret_cast<uint32_t*>(&Vlds[c0 + j][sl]) = pv;
            }
        }
        __syncthreads();

        // issue next tile's predicated global loads (latency hides under MFMA)
        if (ss + TS < steps) {
            const int sn = ss + TS + sl;
            const int s0 = s_begin + sn;
            lv0 = (Msk[sn] == 0);
            lv1 = (Msk[sn + 1] == 0);
            kq0 = z4; kq1 = z4; vq0 = z4; vq1 = z4;
            if (lv0) {
                kq0 = *reinterpret_cast<const float4*>(kb + (size_t)s0 * (NN * DD) + c0);
                vq0 = *reinterpret_cast<const float4*>(vb + (size_t)s0 * (NN * MM) + c0);
            }
            if (lv1) {
                kq1 = *reinterpret_cast<const float4*>(kb + (size_t)(s0 + 1) * (NN * DD) + c0);
                vq1 = *reinterpret_cast<const float4*>(vb + (size_t)(s0 + 1) * (NN * MM) + c0);
            }
        }

        // fragments: A = V^T (rows m), B = K^T (rows d); 8 contiguous s each
        const bf16x8 a0 = *reinterpret_cast<const bf16x8*>(&Vlds[wm + lr][g * 8]);
        const bf16x8 a1 = *reinterpret_cast<const bf16x8*>(&Vlds[wm + 16 + lr][g * 8]);
        const bf16x8 b0 = *reinterpret_cast<const bf16x8*>(&Klds[wd + lr][g * 8]);
        const bf16x8 b1 = *reinterpret_cast<const bf16x8*>(&Klds[wd + 16 + lr][g * 8]);
        acc[0][0] = __builtin_amdgcn_mfma_f32_16x16x32_bf16(a0, b0, acc[0][0], 0, 0, 0);
        acc[0][1] = __builtin_amdgcn_mfma_f32_16x16x32_bf16(a0, b1, acc[0][1], 0, 0, 0);
        acc[1][0] = __builtin_amdgcn_mfma_f32_16x16x32_bf16(a1, b0, acc[1][0], 0, 0, 0);
        acc[1][1] = __builtin_amdgcn_mfma_f32_16x16x32_bf16(a1, b1, acc[1][1], 0, 0, 0);
        __syncthreads();
    }

    // partials: 4096 Sst + 64 Z per (bn, c)
    float* out = ws + ((size_t)bn * C + c) * 4160;

    // C/D layout: col = lane&15, row = (lane>>4)*4 + reg
    #pragma unroll
    for (int i = 0; i < 2; ++i)
        #pragma unroll
        for (int j = 0; j < 2; ++j)
            #pragma unroll
            for (int r = 0; r < 4; ++r) {
                const int m = wm + 16 * i + g * 4 + r;
                const int d = wd + 16 * j + lr;
                out[m * DD + d] = acc[i][j][r];
            }

    *reinterpret_cast<float4*>(&Zred[p][c0]) =
        make_float4(zacc[0], zacc[1], zacc[2], zacc[3]);
    __syncthreads();
    if (t < DD) {
        float z = 0.f;
        #pragma unroll
        for (int q = 0; q < 16; ++q) z += Zred[q][t];
        out[4096 + t] = z;
    }
}

// One block per (bn, m-quarter): reduce C partials for 16 m-rows, emit Sst
// (and Z from quarter 0), then QZ and V. Thread t: d0=(t&15)*4, one m-row
// per 16-lane group.
__global__ __launch_bounds__(256)
void rcla_final(const float* __restrict__ query,
                const float* __restrict__ ws, int C,
                float* __restrict__ outV, float* __restrict__ outS,
                float* __restrict__ outZ) {
    const int q   = blockIdx.x & 3;
    const int bn  = blockIdx.x >> 2;
    const int t   = threadIdx.x;
    const int d0  = (t & 15) << 2;
    const int mr  = (q << 4) + (t >> 4);
    const float* p0 = ws + (size_t)bn * C * 4160;

    float sst[4] = {0.f, 0.f, 0.f, 0.f};
    float z[4]   = {0.f, 0.f, 0.f, 0.f};

    for (int c = 0; c < C; ++c) {
        const float* p = p0 + (size_t)c * 4160;
        const float4 v = *reinterpret_cast<const float4*>(p + mr * DD + d0);
        sst[0] += v.x; sst[1] += v.y; sst[2] += v.z; sst[3] += v.w;
        const float4 zv = *reinterpret_cast<const float4*>(p + 4096 + d0);
        z[0] += zv.x; z[1] += zv.y; z[2] += zv.z; z[3] += zv.w;
    }

    // Output 1: Sst [b,n,m,d]
    *reinterpret_cast<float4*>(outS + (size_t)bn * 4096 + mr * DD + d0) =
        make_float4(sst[0], sst[1], sst[2], sst[3]);
    // Output 2: Z [b,n,d] (quarter 0, group 0 holds lanes for all d)
    if (q == 0 && t < 16) {
        *reinterpret_cast<float4*>(outZ + (size_t)bn * DD + d0) =
            make_float4(z[0], z[1], z[2], z[3]);
    }

    float qf[4];
    #pragma unroll
    for (int j = 0; j < 4; ++j) qf[j] = feat(query[(size_t)bn * DD + d0 + j]);

    // QZ: dot(feat(q), Z) reduced across the 16 lanes of each group
    float pd = qf[0]*z[0] + qf[1]*z[1] + qf[2]*z[2] + qf[3]*z[3];
    float pv = qf[0]*sst[0] + qf[1]*sst[1] + qf[2]*sst[2] + qf[3]*sst[3];
    #pragma unroll
    for (int off = 1; off < 16; off <<= 1) {
        pd += __shfl_xor(pd, off);
        pv += __shfl_xor(pv, off);
    }
    if ((t & 15) == 0) {
        const float qz = 1.0f / (pd + 1e-6f);
        outV[(size_t)bn * MM + mr] = qz * pv;
    }
}

extern "C" void kernel_launch(void* const* d_in, const int* in_sizes, int n_in,
                              void* d_out, int out_size, void* d_ws, size_t ws_size,
                              hipStream_t stream) {
    const float* query = (const float*)d_in[0];
    const float* key   = (const float*)d_in[1];
    const float* value = (const float*)d_in[2];
    const int*   mask  = (const int*)d_in[3];

    float* out  = (float*)d_out;
    float* outV = out;                         // [B,N,M]   8192
    float* outS = out + BB * NN * MM;          // [B,N,M,D] 524288
    float* outZ = outS + BB * NN * MM * DD;    // [B,N,D]   8192
    float* ws   = (float*)d_ws;

    int C = 16;   // 2048 blocks -> 8 blocks/CU (32 waves/CU, HW cap)
    while (C > 8 && (size_t)BB * NN * C * 4160 * sizeof(float) > ws_size) C >>= 1;

    rcla_partial<<<dim3(BB * NN * C), dim3(256), 0, stream>>>(key, value, mask, ws, C);
    rcla_final<<<dim3(BB * NN * 4), dim3(256), 0, stream>>>(query, ws, C, outV, outS, outZ);
}